// Round 8
// baseline (299.404 us; speedup 1.0000x reference)
//
#include <hip/hip_runtime.h>
#include <hip/hip_bf16.h>
#include <math.h>
#include <stdint.h>

typedef unsigned short u16;
typedef __attribute__((ext_vector_type(8))) short bf16x8;
typedef __attribute__((ext_vector_type(4))) float f32x4;
typedef __attribute__((ext_vector_type(4))) unsigned short u16x4;

#define MFMA_BF16(A, B, C) __builtin_amdgcn_mfma_f32_16x16x32_bf16((A), (B), (C), 0, 0, 0)

__device__ __forceinline__ void async16(const void* g, const void* l) {
    __builtin_amdgcn_global_load_lds(
        (const __attribute__((address_space(1))) unsigned int*)(uintptr_t)g,
        (__attribute__((address_space(3))) unsigned int*)(uintptr_t)l, 16, 0, 0);
}

__device__ __forceinline__ u16 f2bf(float f) {
    unsigned u = __float_as_uint(f);
    u += 0x7fffu + ((u >> 16) & 1u);
    return (u16)(u >> 16);
}

__device__ __forceinline__ unsigned pack2(float a, float b) {
    __hip_bfloat162 h = __float22bfloat162_rn(float2{a, b});
    return *reinterpret_cast<unsigned*>(&h);
}

__device__ __forceinline__ float bf2f(u16 v) {
    unsigned u = ((unsigned)v) << 16;
    return __uint_as_float(u);
}

// mix two bf16 pairs: out = l + a*(s-l)
__device__ __forceinline__ unsigned mixpk(unsigned s, unsigned l, float a) {
    float s0 = bf2f((u16)s), s1 = bf2f((u16)(s >> 16));
    float l0 = bf2f((u16)l), l1 = bf2f((u16)(l >> 16));
    return pack2(l0 + a * (s0 - l0), l1 + a * (s1 - l1));
}

// ---------------------------------------------------------------------------
// Converters, one launch. cx<192: weight transpose tiles. cx>=192: x convert.
// ---------------------------------------------------------------------------
__global__ __launch_bounds__(256) void cvt_all(
    const float* __restrict__ x, const float* __restrict__ Wq,
    const float* __restrict__ Wks, const float* __restrict__ Wkl,
    const float* __restrict__ Wo, u16* __restrict__ xb,
    u16* __restrict__ wqt, u16* __restrict__ wkst,
    u16* __restrict__ wklt, u16* __restrict__ wot)
{
    __shared__ float tile[32][33];
    const int cx = blockIdx.x, cy = blockIdx.y, t = threadIdx.x;
    if (cx >= 192) {
        int id = (cx - 192) * 32 + cy;
        size_t base = (size_t)id * 4096 + (size_t)t * 16;
        const float4* src = (const float4*)(x + base);
        u16x4* dst = (u16x4*)(xb + base);
#pragma unroll
        for (int i = 0; i < 4; i++) {
            float4 v = src[i];
            u16x4 o = {f2bf(v.x), f2bf(v.y), f2bf(v.z), f2bf(v.w)};
            dst[i] = o;
        }
        return;
    }
    const float* W; u16* Wt; int N, nb;
    if (cx < 32)       { W = Wq;  Wt = wqt;  N = 1024; nb = cx * 32; }
    else if (cx < 96)  { W = Wks; Wt = wkst; N = 2048; nb = (cx - 32) * 32; }
    else if (cx < 160) { W = Wkl; Wt = wklt; N = 2048; nb = (cx - 96) * 32; }
    else               { W = Wo;  Wt = wot;  N = 1024; nb = (cx - 160) * 32; }
    int kb = cy * 32;
    int r = t >> 3, c4 = (t & 7) * 4;
    float4 v = *(const float4*)&W[(size_t)(kb + r) * N + nb + c4];
    tile[r][c4] = v.x; tile[r][c4 + 1] = v.y;
    tile[r][c4 + 2] = v.z; tile[r][c4 + 3] = v.w;
    __syncthreads();
    u16x4 o = {f2bf(tile[c4 + 0][r]), f2bf(tile[c4 + 1][r]),
               f2bf(tile[c4 + 2][r]), f2bf(tile[c4 + 3][r])};
    *(u16x4*)&Wt[(size_t)(nb + r) * 1024 + kb + c4] = o;
}

// ---------------------------------------------------------------------------
// Fused projection GEMM. Q pre-scaled by 0.125*log2(e).
// K-type blocks (Q, K cols) compute C^T (A=W, B=x) -> u16x4 head-major
// stores. V-type blocks compute C -> u16x4 transposed [B,16,64,L] stores.
// ---------------------------------------------------------------------------
__global__ __launch_bounds__(256) void gemm_proj(
    const u16* __restrict__ A, const u16* __restrict__ wq,
    const u16* __restrict__ wks, const u16* __restrict__ wkl,
    u16* __restrict__ qd, u16* __restrict__ ksd, u16* __restrict__ vsd,
    u16* __restrict__ kld, u16* __restrict__ vld)
{
    __shared__ u16 Alds[128][32];   // x rows (tokens)
    __shared__ u16 Blds[128][32];   // W rows (features)
    const int cx = blockIdx.x;
    const u16* Bt; u16* dK; u16* dV; int colBase; float osc = 1.0f;
    bool ktype;
    if (cx < 8)       { Bt = wq;  colBase = cx * 128;        dK = qd;  dV = nullptr;
                        osc = 0.18033688f; ktype = true; }
    else if (cx < 24) { Bt = wks; colBase = (cx - 8) * 128;  dK = ksd; dV = vsd;
                        ktype = (cx < 16); }
    else              { Bt = wkl; colBase = (cx - 24) * 128; dK = kld; dV = vld;
                        ktype = (cx < 32); }

    const int t = threadIdx.x;
    const int l = t & 63, w = t >> 6;
    const int wm = w & 1, wn = w >> 1;
    const int rowBase = blockIdx.y * 128;
    const int lc = l & 15, lr4 = l >> 4;

    f32x4 acc[4][4];
#pragma unroll
    for (int i = 0; i < 4; i++)
#pragma unroll
        for (int j = 0; j < 4; j++) acc[i][j] = (f32x4){0.f, 0.f, 0.f, 0.f};

    const int srow = w * 32 + (l >> 2);
    const int sc8  = (((l & 3) ^ ((l >> 2) & 3)) * 8);
    const u16* Ag = A  + (size_t)(rowBase + srow) * 1024 + sc8;
    const u16* Bg = Bt + (size_t)(colBase + srow) * 1024 + sc8;
    const int sw = (lc & 3);

    const u16 (*Lm)[32] = ktype ? Blds : Alds;
    const u16 (*Ln)[32] = ktype ? Alds : Blds;

    for (int kt = 0; kt < 32; ++kt) {
        __syncthreads();
        const int ko = kt * 32;
        async16(Ag + ko,         &Alds[w * 32][0]);
        async16(Ag + ko + 16384, &Alds[w * 32 + 16][0]);
        async16(Bg + ko,         &Blds[w * 32][0]);
        async16(Bg + ko + 16384, &Blds[w * 32 + 16][0]);
        __syncthreads();

        bf16x8 af[4], bf[4];
#pragma unroll
        for (int mt = 0; mt < 4; ++mt)
            af[mt] = *(const bf16x8*)&Lm[wm * 64 + mt * 16 + lc][(lr4 ^ sw) * 8];
#pragma unroll
        for (int nt = 0; nt < 4; ++nt)
            bf[nt] = *(const bf16x8*)&Ln[wn * 64 + nt * 16 + lc][(lr4 ^ sw) * 8];
#pragma unroll
        for (int mt = 0; mt < 4; ++mt)
#pragma unroll
            for (int nt = 0; nt < 4; ++nt)
                acc[mt][nt] = MFMA_BF16(af[mt], bf[nt], acc[mt][nt]);
    }

    if (ktype) {
#pragma unroll
        for (int mt = 0; mt < 4; ++mt)
#pragma unroll
            for (int nt = 0; nt < 4; ++nt) {
                int f   = colBase + wm * 64 + mt * 16 + lr4 * 4;
                int tok = rowBase + wn * 64 + nt * 16 + lc;
                int b = tok >> 10, tk = tok & 1023;
                int head = (f >> 6) & 15, d = f & 63;
                u16x4 pv = {f2bf(acc[mt][nt][0] * osc), f2bf(acc[mt][nt][1] * osc),
                            f2bf(acc[mt][nt][2] * osc), f2bf(acc[mt][nt][3] * osc)};
                *(u16x4*)&dK[((size_t)(b * 16 + head) * 1024 + tk) * 64 + d] = pv;
            }
    } else {
#pragma unroll
        for (int mt = 0; mt < 4; ++mt)
#pragma unroll
            for (int nt = 0; nt < 4; ++nt) {
                int gr0 = rowBase + wm * 64 + mt * 16 + lr4 * 4;
                int gc0 = colBase + wn * 64 + nt * 16;
                int head = gc0 >> 6;            // 16..31
                int b = gr0 >> 10, tok = gr0 & 1023;
                int d = (gc0 & 63) + lc;
                u16x4 pv = {f2bf(acc[mt][nt][0]), f2bf(acc[mt][nt][1]),
                            f2bf(acc[mt][nt][2]), f2bf(acc[mt][nt][3])};
                *(u16x4*)&dV[((size_t)(b * 16 + head - 16) * 64 + d) * 1024 +
                             tok] = pv;
            }
    }
}

// ---------------------------------------------------------------------------
// Output GEMM with FUSED MIX: A = alpha*Os + (1-alpha)*Ol mixed during
// LDS staging (store at SWIZZLED position; read undoes it). C^T orientation.
// ---------------------------------------------------------------------------
__global__ __launch_bounds__(256) void gemm_out(
    const u16* __restrict__ Osrc, const u16* __restrict__ Olsrc,
    const u16* __restrict__ Bwot, const float* __restrict__ mixw,
    float* __restrict__ dst)
{
    __shared__ u16 Alds[64][32];    // mixed tokens x k
    __shared__ u16 Blds[128][32];   // Wo features x k
    const int t = threadIdx.x;
    const int l = t & 63, w = t >> 6;
    const int wm = w & 1, wn = w >> 1;
    const int rowBase = blockIdx.y * 64;        // tokens
    const int colBase = blockIdx.x * 128;       // features
    const int lc = l & 15, lr4 = l >> 4;
    const float alpha = 1.0f / (1.0f + __expf(-mixw[0]));

    f32x4 acc[4][2];
#pragma unroll
    for (int i = 0; i < 4; i++)
#pragma unroll
        for (int j = 0; j < 2; j++) acc[i][j] = (f32x4){0.f, 0.f, 0.f, 0.f};

    // A-staging (manual, mixed): thread t loads GLOBAL chunk t&3 of row t>>2
    // and stores it at LDS position (t&3)^(row&3). LDS[row][p] = g[row][p^(row&3)].
    const int arow = t >> 2;
    const int gch  = t & 3;
    const int spos = gch ^ (arow & 3);
    const u16* As = Osrc  + (size_t)(rowBase + arow) * 1024 + gch * 8;
    const u16* Al = Olsrc + (size_t)(rowBase + arow) * 1024 + gch * 8;
    // B-staging via async16
    const int sl  = l >> 2;
    const int sc8 = (((l & 3) ^ (sl & 3)) * 8);
    const u16* Bg = Bwot + (size_t)(colBase + w * 32 + sl) * 1024 + sc8;
    const int sw = (lc & 3);

    for (int kt = 0; kt < 32; ++kt) {
        __syncthreads();
        const int ko = kt * 32;
        uint4 sv = *(const uint4*)(As + ko);
        uint4 lv = *(const uint4*)(Al + ko);
        async16(Bg + ko,         &Blds[w * 32][0]);
        async16(Bg + ko + 16384, &Blds[w * 32 + 16][0]);
        uint4 mv = {mixpk(sv.x, lv.x, alpha), mixpk(sv.y, lv.y, alpha),
                    mixpk(sv.z, lv.z, alpha), mixpk(sv.w, lv.w, alpha)};
        *(uint4*)&Alds[arow][spos * 8] = mv;
        __syncthreads();

        bf16x8 af[4], bf[2];
#pragma unroll
        for (int mt = 0; mt < 4; ++mt)
            af[mt] = *(const bf16x8*)&Blds[wm * 64 + mt * 16 + lc][(lr4 ^ sw) * 8];
#pragma unroll
        for (int nt = 0; nt < 2; ++nt)
            bf[nt] = *(const bf16x8*)&Alds[wn * 32 + nt * 16 + lc][(lr4 ^ sw) * 8];
#pragma unroll
        for (int mt = 0; mt < 4; ++mt)
#pragma unroll
            for (int nt = 0; nt < 2; ++nt)
                acc[mt][nt] = MFMA_BF16(af[mt], bf[nt], acc[mt][nt]);
    }

#pragma unroll
    for (int mt = 0; mt < 4; ++mt)
#pragma unroll
        for (int nt = 0; nt < 2; ++nt) {
            int f   = colBase + wm * 64 + mt * 16 + lr4 * 4;
            int tok = rowBase + wn * 32 + nt * 16 + lc;
            float4 v = {acc[mt][nt][0], acc[mt][nt][1],
                        acc[mt][nt][2], acc[mt][nt][3]};
            *(float4*)&dst[(size_t)tok * 1024 + f] = v;
        }
}

// ---------------------------------------------------------------------------
// Flash attention, BARRIER-FREE: K/V fragments loaded directly from global
// into VGPRs (L2-resident via XCD swizzle); LDS only for the wave-private
// P C->A-layout round-trip. Zero __syncthreads. One branch per block.
// Branch 0 keeps only k-tiles with decay weight > ~2^-20.
// ---------------------------------------------------------------------------
__global__ __launch_bounds__(256, 3) void attn_mfma(
    const u16* __restrict__ Q, const u16* __restrict__ Ksb,
    const u16* __restrict__ Vsb, const u16* __restrict__ Klb,
    const u16* __restrict__ Vlb, const float* __restrict__ decayf,
    u16* __restrict__ Os, u16* __restrict__ Ol)
{
    __shared__ __align__(16) u16 Ps[4][32][72];     // per wave [qrow][krow+pad]

    const int t = threadIdx.x;
    const int l = t & 63, w = t >> 6;
    const int lc = l & 15, lr4 = l >> 4;
    const int h = blockIdx.x, qt = blockIdx.y;
    const int b = blockIdx.z >> 1, branch = blockIdx.z & 1;
    const size_t bh = (size_t)(b * 16 + h);
    const int qbase = qt * 128;
    const u16* Qg = Q + bh * (1024 * 64);
    const u16* Kg = (branch ? Klb : Ksb) + bh * (1024 * 64);
    const u16* Vg = (branch ? Vlb : Vsb) + bh * (64 * 1024);
    u16* outp = branch ? Ol : Os;

    int ktLo = 0, ktHi = 16;
    if (branch == 0) {
        ktLo = 2 * qt - 5; if (ktLo < 0) ktLo = 0;
        ktHi = 2 * qt + 7; if (ktHi > 16) ktHi = 16;
    }

    bf16x8 aQ[2][2];
#pragma unroll
    for (int qg = 0; qg < 2; ++qg)
#pragma unroll
        for (int kh = 0; kh < 2; ++kh)
            aQ[qg][kh] = *(const bf16x8*)&Qg[
                (size_t)(qbase + w * 32 + qg * 16 + lc) * 64 + kh * 32 + lr4 * 8];

    const u16* Kf = Kg + lc * 64 + lr4 * 8;
    const u16* Vf = Vg + lc * 1024 + lr4 * 8;

    const float C2 = (1.0f - decayf[0]) * 1.44269504f;
    const float qf = (float)(qbase + w * 32 + lc);

    float lrun[2] = {0.f, 0.f};
    f32x4 o[2][4];
#pragma unroll
    for (int qg = 0; qg < 2; ++qg)
#pragma unroll
        for (int dt = 0; dt < 4; ++dt) o[qg][dt] = (f32x4){0.f, 0.f, 0.f, 0.f};

    for (int kt = ktLo; kt < ktHi; ++kt) {
        bf16x8 ak[4][2];
#pragma unroll
        for (int nt = 0; nt < 4; ++nt)
#pragma unroll
            for (int kh = 0; kh < 2; ++kh)
                ak[nt][kh] = *(const bf16x8*)(Kf +
                    (size_t)(kt * 64 + nt * 16) * 64 + kh * 32);
        bf16x8 av[4][2];
#pragma unroll
        for (int dt = 0; dt < 4; ++dt)
#pragma unroll
            for (int kh = 0; kh < 2; ++kh)
                av[dt][kh] = *(const bf16x8*)(Vf +
                    (size_t)(dt * 16) * 1024 + kt * 64 + kh * 32);

#pragma unroll
        for (int qg = 0; qg < 2; ++qg) {
            f32x4 s[4];
#pragma unroll
            for (int nt = 0; nt < 4; ++nt) {
                s[nt] = (f32x4){0.f, 0.f, 0.f, 0.f};
                s[nt] = MFMA_BF16(ak[nt][0], aQ[qg][0], s[nt]);
                s[nt] = MFMA_BF16(ak[nt][1], aQ[qg][1], s[nt]);
            }
            const float d0 = qf + (float)(qg * 16 - kt * 64 - lr4 * 4);
            float sum = 0.f;
#pragma unroll
            for (int nt = 0; nt < 4; ++nt) {
                float p[4];
#pragma unroll
                for (int r = 0; r < 4; ++r) {
                    float a = s[nt][r];
                    if (branch == 0)
                        a -= fabsf(d0 - (float)(nt * 16 + r)) * C2;
                    p[r] = __builtin_amdgcn_exp2f(a);
                    sum += p[r];
                }
                uint2 w2 = {pack2(p[0], p[1]), pack2(p[2], p[3])};
                *(uint2*)&Ps[w][qg * 16 + lc][nt * 16 + lr4 * 4] = w2;
            }
            lrun[qg] += sum;
        }

        bf16x8 pb[2][2];
#pragma unroll
        for (int qg = 0; qg < 2; ++qg)
#pragma unroll
            for (int c = 0; c < 2; ++c)
                pb[qg][c] = *(const bf16x8*)&Ps[w][qg * 16 + lc][c * 32 + lr4 * 8];
#pragma unroll
        for (int dt = 0; dt < 4; ++dt)
#pragma unroll
            for (int qg = 0; qg < 2; ++qg) {
                o[qg][dt] = MFMA_BF16(av[dt][0], pb[qg][0], o[qg][dt]);
                o[qg][dt] = MFMA_BF16(av[dt][1], pb[qg][1], o[qg][dt]);
            }
    }

#pragma unroll
    for (int qg = 0; qg < 2; ++qg) {
        float s = lrun[qg];
        s += __shfl_xor(s, 16);
        s += __shfl_xor(s, 32);
        float inv = 1.0f / s;
        int qrow = qbase + w * 32 + qg * 16 + lc;
        u16* op = outp + ((size_t)(b * 1024) + qrow) * 1024 + h * 64;
#pragma unroll
        for (int dt = 0; dt < 4; ++dt) {
            uint2 w2 = {pack2(o[qg][dt][0] * inv, o[qg][dt][1] * inv),
                        pack2(o[qg][dt][2] * inv, o[qg][dt][3] * inv)};
            *(uint2*)&op[dt * 16 + lr4 * 4] = w2;
        }
    }
}

// ---------------------------------------------------------------------------
extern "C" void kernel_launch(void* const* d_in, const int* in_sizes, int n_in,
                              void* d_out, int out_size, void* d_ws, size_t ws_size,
                              hipStream_t stream) {
    const float* x      = (const float*)d_in[0];
    const float* Wq     = (const float*)d_in[1];
    const float* Wkvs   = (const float*)d_in[2];
    const float* Wkvl   = (const float*)d_in[3];
    const float* Wo     = (const float*)d_in[4];
    const float* mixw   = (const float*)d_in[5];
    const float* decayf = (const float*)d_in[6];

    const size_t M1 = 1024 * 1024;
    u16* ws    = (u16*)d_ws;
    u16* xb    = ws;               // 4M  (reused as Os after gemm_proj)
    u16* wqt   = xb + 4 * M1;      // 1M  (wqt..wkvlt reused as Ol)
    u16* wkvst = wqt + 1 * M1;     // 2M
    u16* wkvlt = wkvst + 2 * M1;   // 2M
    u16* wot   = wkvlt + 2 * M1;   // 1M
    u16* qb    = wot + 1 * M1;     // 4M
    u16* ksb   = qb + 4 * M1;      // 4M
    u16* vsb   = ksb + 4 * M1;     // 4M  ([B,16,64,L])
    u16* klb   = vsb + 4 * M1;     // 4M
    u16* vlb   = klb + 4 * M1;     // 4M
    u16* osb   = xb;               // alias: free after gemm_proj
    u16* olb   = wqt;              // alias: free after gemm_proj

    cvt_all<<<dim3(224, 32), 256, 0, stream>>>(x, Wq, Wkvs, Wkvl, Wo, xb,
                                               wqt, wkvst, wkvlt, wot);
    gemm_proj<<<dim3(40, 32), 256, 0, stream>>>(xb, wqt, wkvst, wkvlt,
                                                qb, ksb, vsb, klb, vlb);
    attn_mfma<<<dim3(16, 8, 8), 256, 0, stream>>>(qb, ksb, vsb, klb, vlb,
                                                  decayf, osb, olb);
    gemm_out<<<dim3(8, 64), 256, 0, stream>>>(osb, olb, wot, mixw,
                                              (float*)d_out);
}

// Round 9
// 241.929 us; speedup vs baseline: 1.2376x; 1.2376x over previous
//
#include <hip/hip_runtime.h>
#include <hip/hip_bf16.h>
#include <math.h>
#include <stdint.h>

typedef unsigned short u16;
typedef __attribute__((ext_vector_type(8))) short bf16x8;
typedef __attribute__((ext_vector_type(4))) float f32x4;
typedef __attribute__((ext_vector_type(4))) unsigned short u16x4;

#define MFMA_BF16(A, B, C) __builtin_amdgcn_mfma_f32_16x16x32_bf16((A), (B), (C), 0, 0, 0)

__device__ __forceinline__ void async16(const void* g, const void* l) {
    __builtin_amdgcn_global_load_lds(
        (const __attribute__((address_space(1))) unsigned int*)(uintptr_t)g,
        (__attribute__((address_space(3))) unsigned int*)(uintptr_t)l, 16, 0, 0);
}

__device__ __forceinline__ u16 f2bf(float f) {
    unsigned u = __float_as_uint(f);
    u += 0x7fffu + ((u >> 16) & 1u);
    return (u16)(u >> 16);
}

__device__ __forceinline__ unsigned pack2(float a, float b) {
    __hip_bfloat162 h = __float22bfloat162_rn(float2{a, b});
    return *reinterpret_cast<unsigned*>(&h);
}

__device__ __forceinline__ float bf2f(u16 v) {
    unsigned u = ((unsigned)v) << 16;
    return __uint_as_float(u);
}

// mix two bf16 pairs: out = l + a*(s-l)
__device__ __forceinline__ unsigned mixpk(unsigned s, unsigned l, float a) {
    float s0 = bf2f((u16)s), s1 = bf2f((u16)(s >> 16));
    float l0 = bf2f((u16)l), l1 = bf2f((u16)(l >> 16));
    return pack2(l0 + a * (s0 - l0), l1 + a * (s1 - l1));
}

// ---------------------------------------------------------------------------
// Converters, one launch. cx<192: weight transpose tiles. cx>=192: x convert.
// ---------------------------------------------------------------------------
__global__ __launch_bounds__(256) void cvt_all(
    const float* __restrict__ x, const float* __restrict__ Wq,
    const float* __restrict__ Wks, const float* __restrict__ Wkl,
    const float* __restrict__ Wo, u16* __restrict__ xb,
    u16* __restrict__ wqt, u16* __restrict__ wkst,
    u16* __restrict__ wklt, u16* __restrict__ wot)
{
    __shared__ float tile[32][33];
    const int cx = blockIdx.x, cy = blockIdx.y, t = threadIdx.x;
    if (cx >= 192) {
        int id = (cx - 192) * 32 + cy;
        size_t base = (size_t)id * 4096 + (size_t)t * 16;
        const float4* src = (const float4*)(x + base);
        u16x4* dst = (u16x4*)(xb + base);
#pragma unroll
        for (int i = 0; i < 4; i++) {
            float4 v = src[i];
            u16x4 o = {f2bf(v.x), f2bf(v.y), f2bf(v.z), f2bf(v.w)};
            dst[i] = o;
        }
        return;
    }
    const float* W; u16* Wt; int N, nb;
    if (cx < 32)       { W = Wq;  Wt = wqt;  N = 1024; nb = cx * 32; }
    else if (cx < 96)  { W = Wks; Wt = wkst; N = 2048; nb = (cx - 32) * 32; }
    else if (cx < 160) { W = Wkl; Wt = wklt; N = 2048; nb = (cx - 96) * 32; }
    else               { W = Wo;  Wt = wot;  N = 1024; nb = (cx - 160) * 32; }
    int kb = cy * 32;
    int r = t >> 3, c4 = (t & 7) * 4;
    float4 v = *(const float4*)&W[(size_t)(kb + r) * N + nb + c4];
    tile[r][c4] = v.x; tile[r][c4 + 1] = v.y;
    tile[r][c4 + 2] = v.z; tile[r][c4 + 3] = v.w;
    __syncthreads();
    u16x4 o = {f2bf(tile[c4 + 0][r]), f2bf(tile[c4 + 1][r]),
               f2bf(tile[c4 + 2][r]), f2bf(tile[c4 + 3][r])};
    *(u16x4*)&Wt[(size_t)(nb + r) * 1024 + kb + c4] = o;
}

// ---------------------------------------------------------------------------
// Fused projection GEMM. Q pre-scaled by 0.125*log2(e).
// K-type blocks (Q, K cols) compute C^T (A=W, B=x) -> u16x4 head-major
// stores. V-type blocks compute C -> u16x4 transposed [B,16,64,L] stores.
// ---------------------------------------------------------------------------
__global__ __launch_bounds__(256) void gemm_proj(
    const u16* __restrict__ A, const u16* __restrict__ wq,
    const u16* __restrict__ wks, const u16* __restrict__ wkl,
    u16* __restrict__ qd, u16* __restrict__ ksd, u16* __restrict__ vsd,
    u16* __restrict__ kld, u16* __restrict__ vld)
{
    __shared__ u16 Alds[128][32];   // x rows (tokens)
    __shared__ u16 Blds[128][32];   // W rows (features)
    const int cx = blockIdx.x;
    const u16* Bt; u16* dK; u16* dV; int colBase; float osc = 1.0f;
    bool ktype;
    if (cx < 8)       { Bt = wq;  colBase = cx * 128;        dK = qd;  dV = nullptr;
                        osc = 0.18033688f; ktype = true; }
    else if (cx < 24) { Bt = wks; colBase = (cx - 8) * 128;  dK = ksd; dV = vsd;
                        ktype = (cx < 16); }
    else              { Bt = wkl; colBase = (cx - 24) * 128; dK = kld; dV = vld;
                        ktype = (cx < 32); }

    const int t = threadIdx.x;
    const int l = t & 63, w = t >> 6;
    const int wm = w & 1, wn = w >> 1;
    const int rowBase = blockIdx.y * 128;
    const int lc = l & 15, lr4 = l >> 4;

    f32x4 acc[4][4];
#pragma unroll
    for (int i = 0; i < 4; i++)
#pragma unroll
        for (int j = 0; j < 4; j++) acc[i][j] = (f32x4){0.f, 0.f, 0.f, 0.f};

    const int srow = w * 32 + (l >> 2);
    const int sc8  = (((l & 3) ^ ((l >> 2) & 3)) * 8);
    const u16* Ag = A  + (size_t)(rowBase + srow) * 1024 + sc8;
    const u16* Bg = Bt + (size_t)(colBase + srow) * 1024 + sc8;
    const int sw = (lc & 3);

    const u16 (*Lm)[32] = ktype ? Blds : Alds;
    const u16 (*Ln)[32] = ktype ? Alds : Blds;

    for (int kt = 0; kt < 32; ++kt) {
        __syncthreads();
        const int ko = kt * 32;
        async16(Ag + ko,         &Alds[w * 32][0]);
        async16(Ag + ko + 16384, &Alds[w * 32 + 16][0]);
        async16(Bg + ko,         &Blds[w * 32][0]);
        async16(Bg + ko + 16384, &Blds[w * 32 + 16][0]);
        __syncthreads();

        bf16x8 af[4], bf[4];
#pragma unroll
        for (int mt = 0; mt < 4; ++mt)
            af[mt] = *(const bf16x8*)&Lm[wm * 64 + mt * 16 + lc][(lr4 ^ sw) * 8];
#pragma unroll
        for (int nt = 0; nt < 4; ++nt)
            bf[nt] = *(const bf16x8*)&Ln[wn * 64 + nt * 16 + lc][(lr4 ^ sw) * 8];
#pragma unroll
        for (int mt = 0; mt < 4; ++mt)
#pragma unroll
            for (int nt = 0; nt < 4; ++nt)
                acc[mt][nt] = MFMA_BF16(af[mt], bf[nt], acc[mt][nt]);
    }

    if (ktype) {
#pragma unroll
        for (int mt = 0; mt < 4; ++mt)
#pragma unroll
            for (int nt = 0; nt < 4; ++nt) {
                int f   = colBase + wm * 64 + mt * 16 + lr4 * 4;
                int tok = rowBase + wn * 64 + nt * 16 + lc;
                int b = tok >> 10, tk = tok & 1023;
                int head = (f >> 6) & 15, d = f & 63;
                u16x4 pv = {f2bf(acc[mt][nt][0] * osc), f2bf(acc[mt][nt][1] * osc),
                            f2bf(acc[mt][nt][2] * osc), f2bf(acc[mt][nt][3] * osc)};
                *(u16x4*)&dK[((size_t)(b * 16 + head) * 1024 + tk) * 64 + d] = pv;
            }
    } else {
#pragma unroll
        for (int mt = 0; mt < 4; ++mt)
#pragma unroll
            for (int nt = 0; nt < 4; ++nt) {
                int gr0 = rowBase + wm * 64 + mt * 16 + lr4 * 4;
                int gc0 = colBase + wn * 64 + nt * 16;
                int head = gc0 >> 6;            // 16..31
                int b = gr0 >> 10, tok = gr0 & 1023;
                int d = (gc0 & 63) + lc;
                u16x4 pv = {f2bf(acc[mt][nt][0]), f2bf(acc[mt][nt][1]),
                            f2bf(acc[mt][nt][2]), f2bf(acc[mt][nt][3])};
                *(u16x4*)&dV[((size_t)(b * 16 + head - 16) * 64 + d) * 1024 +
                             tok] = pv;
            }
    }
}

// ---------------------------------------------------------------------------
// Output GEMM with FUSED MIX: A = alpha*Os + (1-alpha)*Ol mixed during
// LDS staging (store at SWIZZLED position; read undoes it). C^T orientation.
// ---------------------------------------------------------------------------
__global__ __launch_bounds__(256) void gemm_out(
    const u16* __restrict__ Osrc, const u16* __restrict__ Olsrc,
    const u16* __restrict__ Bwot, const float* __restrict__ mixw,
    float* __restrict__ dst)
{
    __shared__ u16 Alds[64][32];    // mixed tokens x k
    __shared__ u16 Blds[128][32];   // Wo features x k
    const int t = threadIdx.x;
    const int l = t & 63, w = t >> 6;
    const int wm = w & 1, wn = w >> 1;
    const int rowBase = blockIdx.y * 64;        // tokens
    const int colBase = blockIdx.x * 128;       // features
    const int lc = l & 15, lr4 = l >> 4;
    const float alpha = 1.0f / (1.0f + __expf(-mixw[0]));

    f32x4 acc[4][2];
#pragma unroll
    for (int i = 0; i < 4; i++)
#pragma unroll
        for (int j = 0; j < 2; j++) acc[i][j] = (f32x4){0.f, 0.f, 0.f, 0.f};

    // A-staging: thread t loads GLOBAL chunk t&3 of row t>>2, stores at
    // LDS position (t&3)^(row&3).  LDS[row][p] = g[row][p^(row&3)].
    const int arow = t >> 2;
    const int gch  = t & 3;
    const int spos = gch ^ (arow & 3);
    const u16* As = Osrc  + (size_t)(rowBase + arow) * 1024 + gch * 8;
    const u16* Al = Olsrc + (size_t)(rowBase + arow) * 1024 + gch * 8;
    // B-staging via async16
    const int sl  = l >> 2;
    const int sc8 = (((l & 3) ^ (sl & 3)) * 8);
    const u16* Bg = Bwot + (size_t)(colBase + w * 32 + sl) * 1024 + sc8;
    const int sw = (lc & 3);

    for (int kt = 0; kt < 32; ++kt) {
        __syncthreads();
        const int ko = kt * 32;
        uint4 sv = *(const uint4*)(As + ko);
        uint4 lv = *(const uint4*)(Al + ko);
        async16(Bg + ko,         &Blds[w * 32][0]);
        async16(Bg + ko + 16384, &Blds[w * 32 + 16][0]);
        uint4 mv = {mixpk(sv.x, lv.x, alpha), mixpk(sv.y, lv.y, alpha),
                    mixpk(sv.z, lv.z, alpha), mixpk(sv.w, lv.w, alpha)};
        *(uint4*)&Alds[arow][spos * 8] = mv;
        __syncthreads();

        bf16x8 af[4], bf[2];
#pragma unroll
        for (int mt = 0; mt < 4; ++mt)
            af[mt] = *(const bf16x8*)&Blds[wm * 64 + mt * 16 + lc][(lr4 ^ sw) * 8];
#pragma unroll
        for (int nt = 0; nt < 2; ++nt)
            bf[nt] = *(const bf16x8*)&Alds[wn * 32 + nt * 16 + lc][(lr4 ^ sw) * 8];
#pragma unroll
        for (int mt = 0; mt < 4; ++mt)
#pragma unroll
            for (int nt = 0; nt < 2; ++nt)
                acc[mt][nt] = MFMA_BF16(af[mt], bf[nt], acc[mt][nt]);
    }

#pragma unroll
    for (int mt = 0; mt < 4; ++mt)
#pragma unroll
        for (int nt = 0; nt < 2; ++nt) {
            int f   = colBase + wm * 64 + mt * 16 + lr4 * 4;
            int tok = rowBase + wn * 32 + nt * 16 + lc;
            float4 v = {acc[mt][nt][0], acc[mt][nt][1],
                        acc[mt][nt][2], acc[mt][nt][3]};
            *(float4*)&dst[(size_t)tok * 1024 + f] = v;
        }
}

// ---------------------------------------------------------------------------
// Flash attention (R6-proven structure): transposed-MFMA (S^T, O^T), one
// branch per block, K/V double-buffered LDS prefetch, ONE barrier per iter.
// Q fragments direct from global. Branch-0 window: decay weight > ~2^-20.
// grid = (16 heads, 8 q-tiles, 8 = batch*2+branch) -> XCD-local K/V.
// ---------------------------------------------------------------------------
__global__ __launch_bounds__(256, 3) void attn_mfma(
    const u16* __restrict__ Q, const u16* __restrict__ Ksb,
    const u16* __restrict__ Vsb, const u16* __restrict__ Klb,
    const u16* __restrict__ Vlb, const float* __restrict__ decayf,
    u16* __restrict__ Os, u16* __restrict__ Ol)
{
    __shared__ __align__(16) u16 Kt[2][2][64][32];  // [buf][d-half][krow][32d]
    __shared__ __align__(16) u16 Vt[2][2][64][32];  // [buf][k-half][d][32krow]
    __shared__ __align__(16) u16 Ps[4][32][72];     // per wave [qrow][krow+pad]

    const int t = threadIdx.x;
    const int l = t & 63, w = t >> 6;
    const int lc = l & 15, lr4 = l >> 4;
    const int h = blockIdx.x, qt = blockIdx.y;
    const int b = blockIdx.z >> 1, branch = blockIdx.z & 1;
    const size_t bh = (size_t)(b * 16 + h);
    const int qbase = qt * 128;
    const u16* Qg = Q + bh * (1024 * 64);
    const u16* Kg = (branch ? Klb : Ksb) + bh * (1024 * 64);
    const u16* Vg = (branch ? Vlb : Vsb) + bh * (64 * 1024);
    u16* outp = branch ? Ol : Os;

    const int sl = l >> 2;
    const int sc = (l & 3) * 8;

    // branch-0 window: keep k-tiles with decay weight > ~2^-20
    int ktLo = 0, ktHi = 16;
    if (branch == 0) {
        ktLo = 2 * qt - 5; if (ktLo < 0) ktLo = 0;
        ktHi = 2 * qt + 7; if (ktHi > 16) ktHi = 16;
    }

    // Q B-operand fragments straight from global
    bf16x8 aQ[2][2];
#pragma unroll
    for (int qg = 0; qg < 2; ++qg)
#pragma unroll
        for (int kh = 0; kh < 2; ++kh)
            aQ[qg][kh] = *(const bf16x8*)&Qg[
                (size_t)(qbase + w * 32 + qg * 16 + lc) * 64 + kh * 32 + lr4 * 8];

    auto stage = [&](int kt, int buf) {
#pragma unroll
        for (int i = 0; i < 4; i++) {
            int id = w * 4 + i;
            int kh = (id >> 2) & 1, ch = id & 3;
            if (id < 8)
                async16(Kg + (size_t)(kt * 64 + ch * 16 + sl) * 64 + kh * 32 + sc,
                        &Kt[buf][kh][ch * 16][0]);
            else
                async16(Vg + (size_t)(ch * 16 + sl) * 1024 + kt * 64 + kh * 32 + sc,
                        &Vt[buf][kh][ch * 16][0]);
        }
    };

    stage(ktLo, 0);
    __syncthreads();

    const float C2 = (1.0f - decayf[0]) * 1.44269504f;
    const float qf = (float)(qbase + w * 32 + lc);

    float lrun[2] = {0.f, 0.f};
    f32x4 o[2][4];
#pragma unroll
    for (int qg = 0; qg < 2; ++qg)
#pragma unroll
        for (int dt = 0; dt < 4; ++dt) o[qg][dt] = (f32x4){0.f, 0.f, 0.f, 0.f};

    for (int kt = ktLo, it = 0; kt < ktHi; ++kt, ++it) {
        const int cur = it & 1;
        if (kt + 1 < ktHi) stage(kt + 1, cur ^ 1);

        bf16x8 ak[4][2];
#pragma unroll
        for (int nt = 0; nt < 4; ++nt) {
            ak[nt][0] = *(const bf16x8*)&Kt[cur][0][nt * 16 + lc][lr4 * 8];
            ak[nt][1] = *(const bf16x8*)&Kt[cur][1][nt * 16 + lc][lr4 * 8];
        }

#pragma unroll
        for (int qg = 0; qg < 2; ++qg) {
            f32x4 s[4];
#pragma unroll
            for (int nt = 0; nt < 4; ++nt) {
                s[nt] = (f32x4){0.f, 0.f, 0.f, 0.f};
                s[nt] = MFMA_BF16(ak[nt][0], aQ[qg][0], s[nt]);
                s[nt] = MFMA_BF16(ak[nt][1], aQ[qg][1], s[nt]);
            }
            const float d0 = qf + (float)(qg * 16 - kt * 64 - lr4 * 4);
            float sum = 0.f;
#pragma unroll
            for (int nt = 0; nt < 4; ++nt) {
                float p[4];
#pragma unroll
                for (int r = 0; r < 4; ++r) {
                    float a = s[nt][r];
                    if (branch == 0)
                        a -= fabsf(d0 - (float)(nt * 16 + r)) * C2;
                    p[r] = __builtin_amdgcn_exp2f(a);
                    sum += p[r];
                }
                uint2 w2 = {pack2(p[0], p[1]), pack2(p[2], p[3])};
                *(uint2*)&Ps[w][qg * 16 + lc][nt * 16 + lr4 * 4] = w2;
            }
            lrun[qg] += sum;
        }

        bf16x8 pb[2][2];
#pragma unroll
        for (int qg = 0; qg < 2; ++qg)
#pragma unroll
            for (int c = 0; c < 2; ++c)
                pb[qg][c] = *(const bf16x8*)&Ps[w][qg * 16 + lc][c * 32 + lr4 * 8];
#pragma unroll
        for (int dt = 0; dt < 4; ++dt) {
            bf16x8 v0 = *(const bf16x8*)&Vt[cur][0][dt * 16 + lc][lr4 * 8];
            bf16x8 v1 = *(const bf16x8*)&Vt[cur][1][dt * 16 + lc][lr4 * 8];
#pragma unroll
            for (int qg = 0; qg < 2; ++qg) {
                o[qg][dt] = MFMA_BF16(v0, pb[qg][0], o[qg][dt]);
                o[qg][dt] = MFMA_BF16(v1, pb[qg][1], o[qg][dt]);
            }
        }

        __syncthreads();
    }

#pragma unroll
    for (int qg = 0; qg < 2; ++qg) {
        float s = lrun[qg];
        s += __shfl_xor(s, 16);
        s += __shfl_xor(s, 32);
        float inv = 1.0f / s;
        int qrow = qbase + w * 32 + qg * 16 + lc;
        u16* op = outp + ((size_t)(b * 1024) + qrow) * 1024 + h * 64;
#pragma unroll
        for (int dt = 0; dt < 4; ++dt) {
            uint2 w2 = {pack2(o[qg][dt][0] * inv, o[qg][dt][1] * inv),
                        pack2(o[qg][dt][2] * inv, o[qg][dt][3] * inv)};
            *(uint2*)&op[dt * 16 + lr4 * 4] = w2;
        }
    }
}

// ---------------------------------------------------------------------------
extern "C" void kernel_launch(void* const* d_in, const int* in_sizes, int n_in,
                              void* d_out, int out_size, void* d_ws, size_t ws_size,
                              hipStream_t stream) {
    const float* x      = (const float*)d_in[0];
    const float* Wq     = (const float*)d_in[1];
    const float* Wkvs   = (const float*)d_in[2];
    const float* Wkvl   = (const float*)d_in[3];
    const float* Wo     = (const float*)d_in[4];
    const float* mixw   = (const float*)d_in[5];
    const float* decayf = (const float*)d_in[6];

    const size_t M1 = 1024 * 1024;
    u16* ws    = (u16*)d_ws;
    u16* xb    = ws;               // 4M  (reused as Os after gemm_proj)
    u16* wqt   = xb + 4 * M1;      // 1M  (wqt..wkvlt reused as Ol)
    u16* wkvst = wqt + 1 * M1;     // 2M
    u16* wkvlt = wkvst + 2 * M1;   // 2M
    u16* wot   = wkvlt + 2 * M1;   // 1M
    u16* qb    = wot + 1 * M1;     // 4M
    u16* ksb   = qb + 4 * M1;      // 4M
    u16* vsb   = ksb + 4 * M1;     // 4M  ([B,16,64,L])
    u16* klb   = vsb + 4 * M1;     // 4M
    u16* vlb   = klb + 4 * M1;     // 4M
    u16* osb   = xb;               // alias: free after gemm_proj
    u16* olb   = wqt;              // alias: free after gemm_proj

    cvt_all<<<dim3(224, 32), 256, 0, stream>>>(x, Wq, Wkvs, Wkvl, Wo, xb,
                                               wqt, wkvst, wkvlt, wot);
    gemm_proj<<<dim3(40, 32), 256, 0, stream>>>(xb, wqt, wkvst, wkvlt,
                                                qb, ksb, vsb, klb, vlb);
    attn_mfma<<<dim3(16, 8, 8), 256, 0, stream>>>(qb, ksb, vsb, klb, vlb,
                                                  decayf, osb, olb);
    gemm_out<<<dim3(8, 64), 256, 0, stream>>>(osb, olb, wot, mixw,
                                              (float*)d_out);
}